// Round 2
// baseline (781.853 us; speedup 1.0000x reference)
//
#include <hip/hip_runtime.h>

#define M_ROWS 8192
#define DIN    4096
#define DOUT   4096
#define RANK   32
#define KAUG   4128   // DIN + RANK

typedef __attribute__((ext_vector_type(8))) short short8;
typedef __attribute__((ext_vector_type(4))) float floatx4;

__device__ __forceinline__ unsigned short f2bf(float f) {
    unsigned int u = __float_as_uint(f);
    unsigned int r = (u + 0x7FFFu + ((u >> 16) & 1u)) >> 16;  // RNE
    return (unsigned short)r;
}

// ---------------------------------------------------------------------------
// Kernel 1: per-row sign flip + FWHT(128) + NVFP4 fake-quant -> bf16 Xaug,
//           plus LoRA T = x_rot @ lora_a^T into Xaug[:, 4096:4128].
// One block (256 thr) per row of 4096.
// ---------------------------------------------------------------------------
__global__ __launch_bounds__(256) void rot_quant_kernel(
    const float* __restrict__ x, const float* __restrict__ sgn,
    const float* __restrict__ lora_a, unsigned short* __restrict__ xaug)
{
    __shared__ float xs[4096];
    __shared__ float tred[RANK][9];   // [r][octet] partials (pad to 9)

    const int row = blockIdx.x;
    const int t = threadIdx.x;
    const float* xr = x + (size_t)row * DIN;

    // load + sign flip (float4, coalesced)
    #pragma unroll
    for (int it = 0; it < 4; ++it) {
        int i4 = it * 256 + t;                     // float4 index 0..1023
        float4 v = ((const float4*)xr)[i4];
        float4 s = ((const float4*)sgn)[i4];
        v.x *= s.x; v.y *= s.y; v.z *= s.z; v.w *= s.w;
        ((float4*)xs)[i4] = v;
    }
    __syncthreads();

    // FWHT within each 128-block: stages h = 1..64 (Sylvester order)
    for (int h = 1; h < 128; h <<= 1) {
        #pragma unroll
        for (int p = t; p < 2048; p += 256) {
            int i = ((p & ~(h - 1)) << 1) | (p & (h - 1));
            float a = xs[i], b = xs[i + h];
            xs[i] = a + b;
            xs[i + h] = a - b;
        }
        __syncthreads();
    }

    const float inv = 0.08838834764831845f;  // 1/sqrt(128)

    // NVFP4 fake-quant: thread t owns 16-elem group t
    {
        float v[16];
        float amax = 0.f;
        #pragma unroll
        for (int j = 0; j < 16; ++j) {
            v[j] = xs[16 * t + j] * inv;
            amax = fmaxf(amax, fabsf(v[j]));
        }
        amax = fmaxf(amax, 1e-12f);
        float scale = amax / 6.0f;
        unsigned int pk[8];
        #pragma unroll
        for (int j = 0; j < 8; ++j) {
            unsigned short q2[2];
            #pragma unroll
            for (int e = 0; e < 2; ++e) {
                float vv = v[2 * j + e];
                float an = fabsf(vv) / scale;
                float lev = 0.0f;
                lev = an > 0.25f ? 0.5f : lev;
                lev = an > 0.75f ? 1.0f : lev;
                lev = an > 1.25f ? 1.5f : lev;
                lev = an > 1.75f ? 2.0f : lev;
                lev = an > 2.5f  ? 3.0f : lev;
                lev = an > 3.5f  ? 4.0f : lev;
                lev = an > 5.0f  ? 6.0f : lev;
                q2[e] = f2bf(copysignf(lev * scale, vv));
            }
            pk[j] = (unsigned int)q2[0] | ((unsigned int)q2[1] << 16);
        }
        // 16 bf16 = 32 B per thread, 16B-aligned
        unsigned short* orow = xaug + (size_t)row * KAUG + 16 * t;
        uint4 pk0 = make_uint4(pk[0], pk[1], pk[2], pk[3]);
        uint4 pk1 = make_uint4(pk[4], pk[5], pk[6], pk[7]);
        ((uint4*)orow)[0] = pk0;
        ((uint4*)orow)[1] = pk1;
    }

    // LoRA T: r = t>>3 (0..31), octet = t&7; sum over d
    {
        int r = t >> 3, oct = t & 7;
        const float* ar = lora_a + (size_t)r * DIN;
        float sum = 0.f;
        for (int d0 = oct * 4; d0 < DIN; d0 += 32) {
            float4 a4 = *(const float4*)(ar + d0);
            float4 x4 = *(const float4*)(xs + d0);
            sum += a4.x * x4.x + a4.y * x4.y + a4.z * x4.z + a4.w * x4.w;
        }
        tred[r][oct] = sum;
    }
    __syncthreads();
    if (t < RANK) {
        float s = 0.f;
        #pragma unroll
        for (int k = 0; k < 8; ++k) s += tred[t][k];
        s *= inv;
        xaug[(size_t)row * KAUG + DIN + t] = f2bf(s);
    }
}

// ---------------------------------------------------------------------------
// Kernel 2: Waug[n][0:4096] = bf16(W[n][:]); Waug[n][4096+r] = bf16(lora_b[n][r])
// ---------------------------------------------------------------------------
__global__ __launch_bounds__(256) void cast_w_kernel(
    const float* __restrict__ w, const float* __restrict__ lora_b,
    unsigned short* __restrict__ waug)
{
    const int n = blockIdx.x;
    unsigned short* wr = waug + (size_t)n * KAUG;
    const float* wsrc = w + (size_t)n * DIN;
    #pragma unroll
    for (int j = threadIdx.x; j < DIN; j += 256) wr[j] = f2bf(wsrc[j]);
    if (threadIdx.x < RANK)
        wr[DIN + threadIdx.x] = f2bf(lora_b[(size_t)n * RANK + threadIdx.x]);
}

// ---------------------------------------------------------------------------
// Kernel 3: GEMM  C[8192][4096] = Xaug[8192][4128] * Waug[4096][4128]^T + bias
// m97 structure: 128x128 tile, 4 waves (2x2), each 4x4 of 16x16x32 bf16 MFMA,
// global_load_lds width 16.
// ---------------------------------------------------------------------------
__global__ __launch_bounds__(256) void gemm_kernel(
    const unsigned short* __restrict__ A,   // [8192][4128] bf16 bits
    const unsigned short* __restrict__ Bm,  // [4096][4128] bf16 bits
    const float* __restrict__ bias,
    float* __restrict__ C)                  // [8192][4096]
{
    __shared__ unsigned short As[128 * 32];
    __shared__ unsigned short Bs[128 * 32];

    const int nt = blockIdx.x & 31;          // 32 n-tiles
    const int mt = blockIdx.x >> 5;          // 64 m-tiles
    const int m0 = mt * 128, n0 = nt * 128;
    const int t = threadIdx.x;
    const int wave = t >> 6, lane = t & 63;
    const int wm = wave & 1, wn = wave >> 1; // wave tile 64x64 at (wm,wn)
    const int lm = lane & 15, lq = lane >> 4;

    floatx4 acc[4][4] = {};

    for (int kk = 0; kk < KAUG; kk += 32) {
        __syncthreads();
        // stage: wave w loads chunks 2w, 2w+1 of both tiles (1 KiB each)
        {
            const int c0 = wave * 2;
            const int r_ = (c0 << 4) + (lane >> 2);       // row within tile
            const int colb = (lane & 3) << 3;             // bf16 col offset
            const unsigned short* ga = A + (size_t)(m0 + r_) * KAUG + kk + colb;
            __builtin_amdgcn_global_load_lds(
                (const __attribute__((address_space(1))) void*)ga,
                (__attribute__((address_space(3))) void*)(As + (c0 << 9)), 16, 0, 0);
            __builtin_amdgcn_global_load_lds(
                (const __attribute__((address_space(1))) void*)(ga + (size_t)16 * KAUG),
                (__attribute__((address_space(3))) void*)(As + ((c0 + 1) << 9)), 16, 0, 0);
            const unsigned short* gb = Bm + (size_t)(n0 + r_) * KAUG + kk + colb;
            __builtin_amdgcn_global_load_lds(
                (const __attribute__((address_space(1))) void*)gb,
                (__attribute__((address_space(3))) void*)(Bs + (c0 << 9)), 16, 0, 0);
            __builtin_amdgcn_global_load_lds(
                (const __attribute__((address_space(1))) void*)(gb + (size_t)16 * KAUG),
                (__attribute__((address_space(3))) void*)(Bs + ((c0 + 1) << 9)), 16, 0, 0);
        }
        __syncthreads();

        short8 af[4], bfr[4];
        #pragma unroll
        for (int mi = 0; mi < 4; ++mi)
            af[mi] = *(const short8*)&As[(wm * 64 + mi * 16 + lm) * 32 + lq * 8];
        #pragma unroll
        for (int ni = 0; ni < 4; ++ni)
            bfr[ni] = *(const short8*)&Bs[(wn * 64 + ni * 16 + lm) * 32 + lq * 8];
        #pragma unroll
        for (int mi = 0; mi < 4; ++mi)
            #pragma unroll
            for (int ni = 0; ni < 4; ++ni)
                acc[mi][ni] = __builtin_amdgcn_mfma_f32_16x16x32_bf16(
                    af[mi], bfr[ni], acc[mi][ni], 0, 0, 0);
    }

    // epilogue: += bias, store fp32
    float bv[4];
    #pragma unroll
    for (int ni = 0; ni < 4; ++ni)
        bv[ni] = bias[n0 + wn * 64 + ni * 16 + lm];
    #pragma unroll
    for (int mi = 0; mi < 4; ++mi) {
        #pragma unroll
        for (int ni = 0; ni < 4; ++ni) {
            const int col = n0 + wn * 64 + ni * 16 + lm;
            #pragma unroll
            for (int r = 0; r < 4; ++r) {
                const int rowm = m0 + wm * 64 + mi * 16 + lq * 4 + r;
                C[(size_t)rowm * DOUT + col] = acc[mi][ni][r] + bv[ni];
            }
        }
    }
}

// ---------------------------------------------------------------------------
extern "C" void kernel_launch(void* const* d_in, const int* in_sizes, int n_in,
                              void* d_out, int out_size, void* d_ws, size_t ws_size,
                              hipStream_t stream) {
    const float* x      = (const float*)d_in[0];
    const float* sgn    = (const float*)d_in[1];
    // d_in[2] = H_block (unused; Sylvester Hadamard computed via FWHT)
    const float* w      = (const float*)d_in[3];
    const float* lora_a = (const float*)d_in[4];
    const float* lora_b = (const float*)d_in[5];
    const float* bias   = (const float*)d_in[6];
    float* out = (float*)d_out;

    unsigned short* xaug = (unsigned short*)d_ws;                 // [8192][4128] bf16
    unsigned short* waug = xaug + (size_t)M_ROWS * KAUG;          // [4096][4128] bf16

    rot_quant_kernel<<<M_ROWS, 256, 0, stream>>>(x, sgn, lora_a, xaug);
    cast_w_kernel<<<DOUT, 256, 0, stream>>>(w, lora_b, waug);
    gemm_kernel<<<(M_ROWS / 128) * (DOUT / 128), 256, 0, stream>>>(xaug, waug, bias, out);
}